// Round 5
// baseline (590.869 us; speedup 1.0000x reference)
//
#include <hip/hip_runtime.h>

// Patch2Im col2im (k=7, stride=3), class-decomposed LDS formulation.
//
// h-direction doesn't mix: input row (i,j,ph,:) -> padded output row
// hp = 3*ph + i, and i ≡ hp (mod 3). Output rows of class c = hp%3 use
// i ∈ {c, c+3, c+6} (d = 0,1,2). A block owning rows m = m0..m0+P-1
// (hp = 3m+c) needs from plane (i=c+3d, j) exactly rows [m0-d, m0+P-d):
// a contiguous P*85-float chunk per plane, no halo, each element read once.
// Load 14-21 such chunks (2.7 KB sequential streams) into LDS, then do the
// stride-3 w-scatter as a gather from LDS (phase trick: wp = 3q + rw):
//   rw=0: j=0@pw=q, j=3@pw=q-1, j=6@pw=q-2   (q = t+1)
//   rw=1: j=1@pw=q, j=4@pw=q-1
//   rw=2: j=2@pw=q, j=5@pw=q-1

constexpr int NW    = 85;
constexpr int OH    = 253, OW = 253;
constexpr int PLANE = 85 * 85;        // 7225 floats
constexpr int P     = 8;              // class-rows per block
constexpr int MB    = 11;             // ceil(85/P)
constexpr int PSTR  = P * NW;         // 680 floats: one plane chunk in LDS

__global__ __launch_bounds__(256) void patch2im_kernel(
    const float* __restrict__ x, float* __restrict__ out)
{
    __shared__ float lds[21 * PSTR];  // 57,120 B -> 2 blocks/CU

    int bid = blockIdx.x;
    int mb  = bid % MB;
    int t1  = bid / MB;
    int c   = t1 % 3;                 // row class: hp ≡ c (mod 3)
    int bc  = t1 / 3;

    int m0    = 1 + P * mb;           // hp = 3m + c, m in [1, m_max]
    int nd    = (c == 0) ? 3 : 2;     // i = c + 3d < 7
    int m_max = (c == 0) ? 85 : 84;

    const float* __restrict__ base = x + (size_t)bc * (49 * PLANE);

    // ---- load phase: nd*7 contiguous chunks of P rows each ----
    int total = nd * 7 * PSTR;
    for (int u = threadIdx.x; u < total; u += 256) {
        int pw = u % NW;
        int r  = u / NW;
        int mm = r & (P - 1);         // P = 8
        int pl = r / P;
        int d  = pl / 7;
        int j  = pl - 7 * d;
        int ph = m0 + mm - d;         // global patch row for this lds row
        ph = min(max(ph, 0), 84);     // clamp: stays in-plane; masked in compute
        lds[u] = base[((c + 3 * d) * 7 + j) * PLANE + ph * NW + pw];
    }
    __syncthreads();

    // ---- compute phase: P rows x 85 q-groups, 3 outputs each ----
#define ACC(DD, FD)                                                       \
    {                                                                     \
        const float* L = lds + (DD * 7) * PSTR + mm * NW;                 \
        float v0 = L[0 * PSTR + tp], v1 = L[1 * PSTR + tp],               \
              v2 = L[2 * PSTR + tp], v3 = L[3 * PSTR + t],                \
              v4 = L[4 * PSTR + t],  v5 = L[5 * PSTR + t],                \
              v6 = L[6 * PSTR + tm];                                      \
        o0 += (FD) * (v0 * mR + v3 + v6 * mL);                            \
        o1 += (FD) * (v1 * mR + v4);                                      \
        o2 += (FD) * (v2 * mR + v5);                                      \
    }

    for (int u = threadIdx.x; u < PSTR; u += 256) {
        int t  = u % NW;              // q = t+1 -> w = 3t + rw
        int mm = u / NW;
        int m  = m0 + mm;
        if (m > m_max) continue;      // only last mb block

        float mR = (t <= 83) ? 1.f : 0.f;   // pw = q = t+1 valid
        float mL = (t >= 1)  ? 1.f : 0.f;   // pw = q-2 = t-1 valid
        int   tp = min(t + 1, 84);          // clamped, masked by mR
        int   tm = max(t - 1, 0);           // clamped, masked by mL

        float f0 = (m <= 84) ? 1.f : 0.f;   // d=0 valid (false only c=0,m=85)
        float o0 = 0.f, o1 = 0.f, o2 = 0.f;
        ACC(0, f0)
        ACC(1, 1.f)                          // d=1 always valid for m in [1,85]
        bool nh3 = false;
        if (c == 0) {
            float f2 = (m >= 2) ? 1.f : 0.f; // d=2 valid
            ACC(2, f2)
            nh3 = (f0 != 0.f) && (f2 != 0.f);
        }

        // nh ∈ {2,3}; nw0 = 1+mR+mL ∈ {2,3}; nw1 = nw2 = 2 where written
        float inv2 = nh3 ? (1.f / 6.f) : (1.f / 4.f);        // 1/(2*nh)
        bool  nw3  = (t >= 1) && (t <= 83);
        float inv0 = nh3 ? (nw3 ? (1.f / 9.f) : (1.f / 6.f))
                         : (nw3 ? (1.f / 6.f) : (1.f / 4.f)); // 1/(nh*nw0)

        int h = 3 * m + c - 3;               // output row, [0, 253)
        float* orow = out + ((size_t)bc * OH + h) * OW + 3 * t;
        orow[0] = o0 * inv0;
        if (t < 84) {                        // w = 253,254 don't exist
            orow[1] = o1 * inv2;
            orow[2] = o2 * inv2;
        }
    }
#undef ACC
}

extern "C" void kernel_launch(void* const* d_in, const int* in_sizes, int n_in,
                              void* d_out, int out_size, void* d_ws, size_t ws_size,
                              hipStream_t stream) {
    const float* x = (const float*)d_in[0];
    float* out = (float*)d_out;

    int blocks = 256 * 3 * MB;               // bc * class * m-blocks = 8448
    patch2im_kernel<<<blocks, 256, 0, stream>>>(x, out);
}